// Round 13
// baseline (2784.905 us; speedup 1.0000x reference)
//
#include <hip/hip_runtime.h>
#include <stdint.h>

#define BATCH 8
#define NPTS 4096
#define KNN 20
#define TILE 64
#define NTILES (NPTS / TILE)              // 64: full scan, no splits
#define BTHR 256                          // knn block threads (64 queries)
#define CAP 4                             // FIFO flush trigger
#define CAPMAX 8                          // FIFO capacity (CAP-1+4 <= 8)
constexpr float SLOPE = 0.2f;

typedef unsigned long long u64;
// hi word unpacks to FLT_MAX (finite, NOT NaN) -> threshold stays permissive
// until the list holds 20 real entries. (R2 lesson: NaN kills the filter.)
#define INIT_KEY 0xFF7FFFFFFFFFFFFFULL

// ---------------------------------------------------------------------------
// squared norms
// ---------------------------------------------------------------------------
template<int D>
__global__ __launch_bounds__(256) void sq_kernel(const float* __restrict__ X,
                                                 float* __restrict__ sq) {
    const int i = blockIdx.x * 256 + threadIdx.x;
    if constexpr (D == 3) {
        const float* p = X + (size_t)i * 3;
        sq[i] = p[0] * p[0] + p[1] * p[1] + p[2] * p[2];
    } else {
        const float4* p = (const float4*)(X + (size_t)i * 64);
        float s = 0.f;
        #pragma unroll
        for (int k = 0; k < 16; ++k) {
            float4 v = p[k];
            s += v.x * v.x; s += v.y * v.y; s += v.z * v.z; s += v.w * v.w;
        }
        sq[i] = s;
    }
}

// ---------------------------------------------------------------------------
// key packing: monotone float bits << 32 | j  (min == nearest, ties -> low j)
// ---------------------------------------------------------------------------
__device__ __forceinline__ u64 pack_key(float d, unsigned j) {
    unsigned ub = __float_as_uint(d);
    ub = (ub & 0x80000000u) ? ~ub : (ub | 0x80000000u);
    return ((u64)ub << 32) | j;
}
__device__ __forceinline__ float key_hi_to_d(unsigned hi) {
    unsigned u = (hi & 0x80000000u) ? (hi ^ 0x80000000u) : ~hi;
    return __uint_as_float(u);
}
__device__ __forceinline__ void insert_key(u64 (&lst)[KNN], u64 c) {
    #pragma unroll
    for (int k = 0; k < KNN; ++k) {
        const u64 lo = (lst[k] < c) ? lst[k] : c;
        const u64 hi = (lst[k] < c) ? c : lst[k];
        lst[k] = lo; c = hi;
    }
}
// buft = &buf[t]. GROUP-MIN threshold (R12): tmax = min over the query's 4
// lanes of their lane-20ths (exact: min(lane-20ths) >= union-20th).
__device__ __forceinline__ void flush_buf(u64 (&lst)[KNN], const u64* __restrict__ buft,
                                          int& cnt, float& tmax) {
    for (int i = 0; i < CAPMAX; ++i) {
        if (!__any(i < cnt)) break;          // wave-uniform early exit
        if (i < cnt) {
            const u64 key = buft[i * BTHR];
            if (key < lst[KNN - 1]) insert_key(lst, key);
        }
    }
    cnt = 0;
    float m = key_hi_to_d((unsigned)(lst[KNN - 1] >> 32));
    m = fminf(m, __shfl_xor(m, 1));
    m = fminf(m, __shfl_xor(m, 2));
    tmax = m;
}

// ---------------------------------------------------------------------------
// kNN v3.5 (R12 best): 4x4-microtile distance GEMM + threshold/FIFO
// selection with group-min threshold. Unchanged this round.
// ---------------------------------------------------------------------------
template<int D>   // 3 or 64
__global__ __launch_bounds__(BTHR) void knn3_kernel(
    const float* __restrict__ X, const float* __restrict__ sq,
    int* __restrict__ knn_idx)        // [B*N][20]
{
    __shared__ alignas(16) float smem[17280];
    float* xq   = smem;
    float* xj   = smem + 4352;
    float* dist = smem + 8704;
    float* sqq  = smem + 13056;
    float* sqj  = smem + 13120;
    u64*   buf  = (u64*)(smem + 13184);
    u64*   lists = (u64*)smem;

    const int t = threadIdx.x;
    const int b = blockIdx.y;
    const int qbase = blockIdx.x * 64;
    const float* Xb  = X  + (size_t)b * NPTS * D;
    const float* sqb = sq + (size_t)b * NPTS;

    const int qg = t >> 4, jg = t & 15;   // phase A mapping
    const int q  = t >> 2, s  = t & 3;    // phase B mapping

    float4 aq[(D == 3) ? 4 : 1];
    float sqq_r[4];
    if constexpr (D == 3) {
        #pragma unroll
        for (int rr = 0; rr < 4; ++rr) {
            const float* qp = Xb + (size_t)(qbase + 4 * qg + rr) * 3;
            aq[rr].x = qp[0]; aq[rr].y = qp[1]; aq[rr].z = qp[2]; aq[rr].w = 0.f;
            sqq_r[rr] = sqb[qbase + 4 * qg + rr];
        }
        if (t < 64) {
            const float* row = Xb + (size_t)t * 3;
            xj[0 * 68 + t] = row[0];
            xj[1 * 68 + t] = row[1];
            xj[2 * 68 + t] = row[2];
            sqj[t] = sqb[t];
        }
    } else {
        #pragma unroll
        for (int ci = t; ci < 1024; ci += BTHR) {
            const int r = ci >> 4, c4 = ci & 15;
            *(float4*)&xq[r * 68 + 4 * c4] =
                *(const float4*)&Xb[(size_t)(qbase + r) * 64 + 4 * c4];
        }
        #pragma unroll
        for (int ci = t; ci < 1024; ci += BTHR) {
            const int r = ci >> 4, c4 = ci & 15;
            const int c4s = (c4 + (r >> 2)) & 15;      // additive rotation
            *(float4*)&xj[r * 68 + 4 * c4s] =
                *(const float4*)&Xb[(size_t)r * 64 + 4 * c4];
        }
        if (t < 64) { sqq[t] = sqb[qbase + t]; sqj[t] = sqb[t]; }
    }
    __syncthreads();
    if constexpr (D != 3) {
        #pragma unroll
        for (int rr = 0; rr < 4; ++rr) sqq_r[rr] = sqq[4 * qg + rr];
    }

    const float* aP0 = &xq[(4 * qg + 0) * 68];
    const float* aP1 = &xq[(4 * qg + 1) * 68];
    const float* aP2 = &xq[(4 * qg + 2) * 68];
    const float* aP3 = &xq[(4 * qg + 3) * 68];
    const float* bP0 = &xj[(4 * jg + 0) * 68];
    const float* bP1 = &xj[(4 * jg + 1) * 68];
    const float* bP2 = &xj[(4 * jg + 2) * 68];
    const float* bP3 = &xj[(4 * jg + 3) * 68];
    float* dW = &dist[4 * qg * 68 + 4 * jg];
    const float* drow = &dist[q * 68 + s * 16];
    const float* sjP = &sqj[4 * jg];
    u64* const buft = buf + t;
    u64* bufc = buft;

    u64 lst[KNN];
    #pragma unroll
    for (int k = 0; k < KNN; ++k) lst[k] = INIT_KEY;
    float tmax = 3.402823466e38f;
    int cnt = 0;

    for (int tile = 0; tile < NTILES; ++tile) {
        if constexpr (D == 3) {
            float sj[4];
            #pragma unroll
            for (int cc = 0; cc < 4; ++cc) sj[cc] = sjP[cc];
            float4 bx, by, bz;
            bx.x = xj[0 * 68 + 4 * jg + 0]; bx.y = xj[0 * 68 + 4 * jg + 1];
            bx.z = xj[0 * 68 + 4 * jg + 2]; bx.w = xj[0 * 68 + 4 * jg + 3];
            by.x = xj[1 * 68 + 4 * jg + 0]; by.y = xj[1 * 68 + 4 * jg + 1];
            by.z = xj[1 * 68 + 4 * jg + 2]; by.w = xj[1 * 68 + 4 * jg + 3];
            bz.x = xj[2 * 68 + 4 * jg + 0]; bz.y = xj[2 * 68 + 4 * jg + 1];
            bz.z = xj[2 * 68 + 4 * jg + 2]; bz.w = xj[2 * 68 + 4 * jg + 3];
            #pragma unroll
            for (int rr = 0; rr < 4; ++rr) {
                float4 dv;
                dv.x = sqq_r[rr] + sj[0] - 2.f * (aq[rr].x * bx.x + aq[rr].y * by.x + aq[rr].z * bz.x);
                dv.y = sqq_r[rr] + sj[1] - 2.f * (aq[rr].x * bx.y + aq[rr].y * by.y + aq[rr].z * bz.y);
                dv.z = sqq_r[rr] + sj[2] - 2.f * (aq[rr].x * bx.z + aq[rr].y * by.z + aq[rr].z * bz.z);
                dv.w = sqq_r[rr] + sj[3] - 2.f * (aq[rr].x * bx.w + aq[rr].y * by.w + aq[rr].z * bz.w);
                *(float4*)&dW[rr * 68] = dv;
            }
        } else {
            float acc[4][4];
            #pragma unroll
            for (int rr = 0; rr < 4; ++rr)
                #pragma unroll
                for (int cc = 0; cc < 4; ++cc) acc[rr][cc] = 0.f;
            #pragma unroll
            for (int k = 0; k < 16; ++k) {
                const int ko = 4 * k;
                const int kxo = 4 * ((k + jg) & 15);
                float4 a[4], bv[4];
                a[0] = *(const float4*)&aP0[ko];
                a[1] = *(const float4*)&aP1[ko];
                a[2] = *(const float4*)&aP2[ko];
                a[3] = *(const float4*)&aP3[ko];
                bv[0] = *(const float4*)&bP0[kxo];
                bv[1] = *(const float4*)&bP1[kxo];
                bv[2] = *(const float4*)&bP2[kxo];
                bv[3] = *(const float4*)&bP3[kxo];
                #pragma unroll
                for (int rr = 0; rr < 4; ++rr)
                    #pragma unroll
                    for (int cc = 0; cc < 4; ++cc) {
                        float v = acc[rr][cc];
                        v = fmaf(a[rr].x, bv[cc].x, v);
                        v = fmaf(a[rr].y, bv[cc].y, v);
                        v = fmaf(a[rr].z, bv[cc].z, v);
                        v = fmaf(a[rr].w, bv[cc].w, v);
                        acc[rr][cc] = v;
                    }
            }
            float sj[4];
            #pragma unroll
            for (int cc = 0; cc < 4; ++cc) sj[cc] = sjP[cc];
            #pragma unroll
            for (int rr = 0; rr < 4; ++rr) {
                float4 dv;
                dv.x = sqq_r[rr] + sj[0] - 2.f * acc[rr][0];
                dv.y = sqq_r[rr] + sj[1] - 2.f * acc[rr][1];
                dv.z = sqq_r[rr] + sj[2] - 2.f * acc[rr][2];
                dv.w = sqq_r[rr] + sj[3] - 2.f * acc[rr][3];
                *(float4*)&dW[rr * 68] = dv;
            }
        }
        __syncthreads();   // barrier1: dist ready; xj consumed

        if (tile + 1 < NTILES) {
            const int cb = (tile + 1) * TILE;
            if constexpr (D == 3) {
                if (t < 64) {
                    const float* row = Xb + (size_t)(cb + t) * 3;
                    xj[0 * 68 + t] = row[0];
                    xj[1 * 68 + t] = row[1];
                    xj[2 * 68 + t] = row[2];
                    sqj[t] = sqb[cb + t];
                }
            } else {
                #pragma unroll
                for (int ci = t; ci < 1024; ci += BTHR) {
                    const int r = ci >> 4, c4 = ci & 15;
                    const int c4s = (c4 + (r >> 2)) & 15;
                    *(float4*)&xj[r * 68 + 4 * c4s] =
                        *(const float4*)&Xb[(size_t)(cb + r) * 64 + 4 * c4];
                }
                if (t < 64) sqj[t] = sqb[cb + t];
            }
        }

        {
            const unsigned cbase = tile * TILE + s * 16;
            #pragma unroll
            for (int g = 0; g < 4; ++g) {
                const float4 dv = *(const float4*)&drow[g * 4];
                if (dv.x <= tmax) { *bufc = pack_key(dv.x, cbase + g * 4 + 0); bufc += BTHR; ++cnt; }
                if (dv.y <= tmax) { *bufc = pack_key(dv.y, cbase + g * 4 + 1); bufc += BTHR; ++cnt; }
                if (dv.z <= tmax) { *bufc = pack_key(dv.z, cbase + g * 4 + 2); bufc += BTHR; ++cnt; }
                if (dv.w <= tmax) { *bufc = pack_key(dv.w, cbase + g * 4 + 3); bufc += BTHR; ++cnt; }
                if (__any(cnt >= CAP)) { flush_buf(lst, buft, cnt, tmax); bufc = buft; }
            }
        }
        __syncthreads();   // barrier2: dist consumed; xj ready for next A
    }
    if (__any(cnt > 0)) flush_buf(lst, buft, cnt, tmax);

    #pragma unroll
    for (int k = 0; k < KNN; ++k) lists[t * KNN + k] = lst[k];
    __syncthreads();

    if (t < 64) {
        const u64* L0 = lists + (size_t)(t * 4 + 0) * KNN;
        const u64* L1 = L0 + KNN;
        const u64* L2 = L1 + KNN;
        const u64* L3 = L2 + KNN;
        int p0 = 0, p1 = 0, p2 = 0, p3 = 0;
        int* outp = knn_idx + ((size_t)b * NPTS + qbase + t) * KNN;
        for (int k = 0; k < KNN; ++k) {
            const u64 h0 = L0[p0], h1 = L1[p1], h2 = L2[p2], h3 = L3[p3];
            const u64 m01 = (h0 < h1) ? h0 : h1;
            const u64 m23 = (h2 < h3) ? h2 : h3;
            const u64 m   = (m01 < m23) ? m01 : m23;
            outp[k] = (int)(unsigned)(m & 0xffffffffu);
            if (m == h0) ++p0; else if (m == h1) ++p1; else if (m == h2) ++p2; else ++p3;
        }
    }
}

// ---------------------------------------------------------------------------
// per-point u = X @ W1b, c = X @ W1a - u + b1
// ---------------------------------------------------------------------------
template<int D>
__global__ __launch_bounds__(256) void uc_kernel(
    const float* __restrict__ X, const float* __restrict__ W1,
    const float* __restrict__ b1, float* __restrict__ u, float* __restrict__ cvec) {
    __shared__ float Xs[16 * D];
    const int n0 = blockIdx.x * 16;
    const int t = threadIdx.x;
    for (int i = t; i < 16 * D; i += 256)
        Xs[i] = X[(size_t)n0 * D + i];
    __syncthreads();

    const int o = t & 63;
    const int pg = t >> 6;
    float va[4] = {0.f, 0.f, 0.f, 0.f};
    float vb[4] = {0.f, 0.f, 0.f, 0.f};
    for (int d = 0; d < D; ++d) {
        const float wa = W1[d * 64 + o];
        const float wb = W1[(D + d) * 64 + o];
        #pragma unroll
        for (int pi = 0; pi < 4; ++pi) {
            const float x = Xs[(pg * 4 + pi) * D + d];
            va[pi] += x * wa;
            vb[pi] += x * wb;
        }
    }
    const float bo = b1[o];
    #pragma unroll
    for (int pi = 0; pi < 4; ++pi) {
        const size_t n = (size_t)n0 + pg * 4 + pi;
        u[n * 64 + o] = vb[pi];
        cvec[n * 64 + o] = va[pi] - vb[pi] + bo;
    }
}

// ---------------------------------------------------------------------------
// fused edge MLP + max aggregation, v2: 8 points (160 edges) per block.
// Halves per-point overheads vs 4-pt version: W staging, barriers, launches.
// Per-output math expression/order identical -> bit-identical results.
// Final max: per-thread 10-row max + __shfl_xor(.,16) pair combine (rg^1 is
// 16 lanes away in the same wave) -> no mxs LDS round-trip.
// ---------------------------------------------------------------------------
__device__ __forceinline__ void gemm_acc10(const float* __restrict__ Xs,
                                           const float* __restrict__ Ws,
                                           const float* __restrict__ bias,
                                           float (&acc)[10][4], const int t) {
    const int rg = t >> 4, og = t & 15;
    #pragma unroll
    for (int oc = 0; oc < 4; ++oc) {
        const float bb = bias[4 * og + oc];
        #pragma unroll
        for (int rr = 0; rr < 10; ++rr) acc[rr][oc] = bb;
    }
    #pragma unroll
    for (int k4 = 0; k4 < 16; ++k4) {
        float4 wv[4];
        #pragma unroll
        for (int kk = 0; kk < 4; ++kk)
            wv[kk] = *(const float4*)&Ws[(4 * k4 + kk) * 64 + 4 * og];
        #pragma unroll
        for (int rr = 0; rr < 10; ++rr) {
            const float4 xv = *(const float4*)&Xs[(10 * rg + rr) * 68 + 4 * k4];
            acc[rr][0] += xv.x * wv[0].x + xv.y * wv[1].x + xv.z * wv[2].x + xv.w * wv[3].x;
            acc[rr][1] += xv.x * wv[0].y + xv.y * wv[1].y + xv.z * wv[2].y + xv.w * wv[3].y;
            acc[rr][2] += xv.x * wv[0].z + xv.y * wv[1].z + xv.z * wv[2].z + xv.w * wv[3].z;
            acc[rr][3] += xv.x * wv[0].w + xv.y * wv[1].w + xv.z * wv[2].w + xv.w * wv[3].w;
        }
    }
}

__global__ __launch_bounds__(256) void edge_kernel(
    const float* __restrict__ u, const float* __restrict__ cvec,
    const int* __restrict__ knn_idx,
    const float* __restrict__ W2, const float* __restrict__ b2,
    const float* __restrict__ W3, const float* __restrict__ b3,
    float* __restrict__ out) {
    __shared__ alignas(16) float h1s[160 * 68];   // 43.5 KB
    __shared__ alignas(16) float Ws[64 * 64];     // 16 KB
    __shared__ float cs[8 * 64];                  // 2 KB
    __shared__ int idxs[160];                     // 0.64 KB  -> 62.6 KB total

    const int t = threadIdx.x;
    const int p0 = blockIdx.x * 8;                // 8 points per block
    const int b = p0 >> 12;

    cs[t] = cvec[(size_t)p0 * 64 + t];
    cs[256 + t] = cvec[(size_t)p0 * 64 + 256 + t];
    if (t < 160) idxs[t] = knn_idx[(size_t)p0 * KNN + t];
    for (int i = t; i < 4096; i += 256) Ws[i] = W2[i];
    __syncthreads();

    {   // h1 = lrelu(c_i + u_j), 160 edges
        const int wave = t >> 6, lane = t & 63;
        for (int e = wave; e < 160; e += 4) {
            const int j = idxs[e];
            const float val = u[((size_t)(b << 12) + j) * 64 + lane];
            const float pre = cs[(e / 20) * 64 + lane] + val;
            h1s[e * 68 + lane] = (pre > 0.f) ? pre : SLOPE * pre;
        }
    }
    __syncthreads();

    float acc[10][4];
    gemm_acc10(h1s, Ws, b2, acc, t);    // GEMM1: 160x64x64
    __syncthreads();

    {   // write h2 back into h1s; stage W3
        const int rg = t >> 4, og = t & 15;
        #pragma unroll
        for (int rr = 0; rr < 10; ++rr)
            #pragma unroll
            for (int oc = 0; oc < 4; ++oc) {
                float v = acc[rr][oc];
                v = (v > 0.f) ? v : SLOPE * v;
                h1s[(10 * rg + rr) * 68 + 4 * og + oc] = v;
            }
        for (int i = t; i < 4096; i += 256) Ws[i] = W3[i];
    }
    __syncthreads();

    gemm_acc10(h1s, Ws, b3, acc, t);    // GEMM2
    {   // max over each thread's 10 rows (within one point: 10 | 20),
        // then combine the two half-point threads via shfl (t ^ 16).
        const int rg = t >> 4, og = t & 15;
        float mx[4];
        #pragma unroll
        for (int oc = 0; oc < 4; ++oc) {
            float m = -1e30f;
            #pragma unroll
            for (int rr = 0; rr < 10; ++rr) {
                float v = acc[rr][oc];
                v = (v > 0.f) ? v : SLOPE * v;
                m = fmaxf(m, v);
            }
            mx[oc] = fmaxf(m, __shfl_xor(m, 16));
        }
        if (!(rg & 1)) {
            float4 o4;
            o4.x = mx[0]; o4.y = mx[1]; o4.z = mx[2]; o4.w = mx[3];
            *(float4*)&out[(size_t)(p0 + (rg >> 1)) * 64 + 4 * og] = o4;
        }
    }
}

// ---------------------------------------------------------------------------
extern "C" void kernel_launch(void* const* d_in, const int* in_sizes, int n_in,
                              void* d_out, int out_size, void* d_ws, size_t ws_size,
                              hipStream_t stream) {
    const float* pos = (const float*)d_in[0];
    const float* w11 = (const float*)d_in[1];  const float* b11 = (const float*)d_in[2];
    const float* w12 = (const float*)d_in[3];  const float* b12 = (const float*)d_in[4];
    const float* w13 = (const float*)d_in[5];  const float* b13 = (const float*)d_in[6];
    const float* w21 = (const float*)d_in[7];  const float* b21 = (const float*)d_in[8];
    const float* w22 = (const float*)d_in[9];  const float* b22 = (const float*)d_in[10];
    const float* w23 = (const float*)d_in[11]; const float* b23 = (const float*)d_in[12];
    const float* w31 = (const float*)d_in[13]; const float* b31 = (const float*)d_in[14];
    const float* w32 = (const float*)d_in[15]; const float* b32 = (const float*)d_in[16];
    const float* w33 = (const float*)d_in[17]; const float* b33 = (const float*)d_in[18];

    const int BN = BATCH * NPTS;   // 32768
    // Simple workspace (no aliasing): [sqb][idx][x1][u][c][x2] = 36.3 MB
    float* ws = (float*)d_ws;
    float* sqb = ws;                                  // [BN]
    int*   idx = (int*)(sqb + BN);                    // [BN][20]
    float* x1  = (float*)(idx + (size_t)BN * KNN);    // [BN][64]
    float* ubuf = x1 + (size_t)BN * 64;               // [BN][64]
    float* cbuf = ubuf + (size_t)BN * 64;             // [BN][64]
    float* x2  = cbuf + (size_t)BN * 64;              // [BN][64]

    const dim3 knn_grid(NPTS / 64, BATCH);            // (64, 8) = 512 blocks

    // ---- EdgeConv 1 (D=3)
    sq_kernel<3><<<BN / 256, 256, 0, stream>>>(pos, sqb);
    knn3_kernel<3><<<knn_grid, BTHR, 0, stream>>>(pos, sqb, idx);
    uc_kernel<3><<<BN / 16, 256, 0, stream>>>(pos, w11, b11, ubuf, cbuf);
    edge_kernel<<<BN / 8, 256, 0, stream>>>(ubuf, cbuf, idx, w12, b12, w13, b13, x1);

    // ---- EdgeConv 2 (D=64)
    sq_kernel<64><<<BN / 256, 256, 0, stream>>>(x1, sqb);
    knn3_kernel<64><<<knn_grid, BTHR, 0, stream>>>(x1, sqb, idx);
    uc_kernel<64><<<BN / 16, 256, 0, stream>>>(x1, w21, b21, ubuf, cbuf);
    edge_kernel<<<BN / 8, 256, 0, stream>>>(ubuf, cbuf, idx, w22, b22, w23, b23, x2);

    // ---- EdgeConv 3 (D=64)
    sq_kernel<64><<<BN / 256, 256, 0, stream>>>(x2, sqb);
    knn3_kernel<64><<<knn_grid, BTHR, 0, stream>>>(x2, sqb, idx);
    uc_kernel<64><<<BN / 16, 256, 0, stream>>>(x2, w31, b31, ubuf, cbuf);
    edge_kernel<<<BN / 8, 256, 0, stream>>>(ubuf, cbuf, idx, w32, b32, w33, b33, (float*)d_out);
}

// Round 14
// 2590.673 us; speedup vs baseline: 1.0750x; 1.0750x over previous
//
#include <hip/hip_runtime.h>
#include <stdint.h>

#define BATCH 8
#define NPTS 4096
#define KNN 20
#define TILE 64
#define NTILES (NPTS / TILE)              // 64: full scan, no splits
#define BTHR 256                          // knn block threads (64 queries)
#define CAP 4                             // FIFO flush trigger
#define CAPMAX 8                          // FIFO capacity (CAP-1+4 <= 8)
constexpr float SLOPE = 0.2f;

typedef unsigned long long u64;
// hi word unpacks to FLT_MAX (finite, NOT NaN) -> threshold stays permissive
// until the list holds 20 real entries. (R2 lesson: NaN kills the filter.)
#define INIT_KEY 0xFF7FFFFFFFFFFFFFULL

// ---------------------------------------------------------------------------
// key packing: monotone float bits << 32 | j  (min == nearest, ties -> low j)
// ---------------------------------------------------------------------------
__device__ __forceinline__ u64 pack_key(float d, unsigned j) {
    unsigned ub = __float_as_uint(d);
    ub = (ub & 0x80000000u) ? ~ub : (ub | 0x80000000u);
    return ((u64)ub << 32) | j;
}
__device__ __forceinline__ float key_hi_to_d(unsigned hi) {
    unsigned u = (hi & 0x80000000u) ? (hi ^ 0x80000000u) : ~hi;
    return __uint_as_float(u);
}
__device__ __forceinline__ void insert_key(u64 (&lst)[KNN], u64 c) {
    #pragma unroll
    for (int k = 0; k < KNN; ++k) {
        const u64 lo = (lst[k] < c) ? lst[k] : c;
        const u64 hi = (lst[k] < c) ? c : lst[k];
        lst[k] = lo; c = hi;
    }
}
// buft = &buf[t]. GROUP-MIN threshold (R12): tmax = min over the query's 4
// lanes of their lane-20ths (exact: min(lane-20ths) >= union-20th).
__device__ __forceinline__ void flush_buf(u64 (&lst)[KNN], const u64* __restrict__ buft,
                                          int& cnt, float& tmax) {
    for (int i = 0; i < CAPMAX; ++i) {
        if (!__any(i < cnt)) break;          // wave-uniform early exit
        if (i < cnt) {
            const u64 key = buft[i * BTHR];
            if (key < lst[KNN - 1]) insert_key(lst, key);
        }
    }
    cnt = 0;
    float m = key_hi_to_d((unsigned)(lst[KNN - 1] >> 32));
    m = fminf(m, __shfl_xor(m, 1));
    m = fminf(m, __shfl_xor(m, 2));
    tmax = m;
}

// ---------------------------------------------------------------------------
// kNN v3.5 (R12 best): 4x4-microtile distance GEMM + threshold/FIFO
// selection with group-min threshold. Unchanged from R12.
// ---------------------------------------------------------------------------
template<int D>   // 3 or 64
__global__ __launch_bounds__(BTHR) void knn3_kernel(
    const float* __restrict__ X, const float* __restrict__ sq,
    int* __restrict__ knn_idx)        // [B*N][20]
{
    __shared__ alignas(16) float smem[17280];
    float* xq   = smem;
    float* xj   = smem + 4352;
    float* dist = smem + 8704;
    float* sqq  = smem + 13056;
    float* sqj  = smem + 13120;
    u64*   buf  = (u64*)(smem + 13184);
    u64*   lists = (u64*)smem;

    const int t = threadIdx.x;
    const int b = blockIdx.y;
    const int qbase = blockIdx.x * 64;
    const float* Xb  = X  + (size_t)b * NPTS * D;
    const float* sqb = sq + (size_t)b * NPTS;

    const int qg = t >> 4, jg = t & 15;   // phase A mapping
    const int q  = t >> 2, s  = t & 3;    // phase B mapping

    float4 aq[(D == 3) ? 4 : 1];
    float sqq_r[4];
    if constexpr (D == 3) {
        #pragma unroll
        for (int rr = 0; rr < 4; ++rr) {
            const float* qp = Xb + (size_t)(qbase + 4 * qg + rr) * 3;
            aq[rr].x = qp[0]; aq[rr].y = qp[1]; aq[rr].z = qp[2]; aq[rr].w = 0.f;
            sqq_r[rr] = sqb[qbase + 4 * qg + rr];
        }
        if (t < 64) {
            const float* row = Xb + (size_t)t * 3;
            xj[0 * 68 + t] = row[0];
            xj[1 * 68 + t] = row[1];
            xj[2 * 68 + t] = row[2];
            sqj[t] = sqb[t];
        }
    } else {
        #pragma unroll
        for (int ci = t; ci < 1024; ci += BTHR) {
            const int r = ci >> 4, c4 = ci & 15;
            *(float4*)&xq[r * 68 + 4 * c4] =
                *(const float4*)&Xb[(size_t)(qbase + r) * 64 + 4 * c4];
        }
        #pragma unroll
        for (int ci = t; ci < 1024; ci += BTHR) {
            const int r = ci >> 4, c4 = ci & 15;
            const int c4s = (c4 + (r >> 2)) & 15;      // additive rotation
            *(float4*)&xj[r * 68 + 4 * c4s] =
                *(const float4*)&Xb[(size_t)r * 64 + 4 * c4];
        }
        if (t < 64) { sqq[t] = sqb[qbase + t]; sqj[t] = sqb[t]; }
    }
    __syncthreads();
    if constexpr (D != 3) {
        #pragma unroll
        for (int rr = 0; rr < 4; ++rr) sqq_r[rr] = sqq[4 * qg + rr];
    }

    const float* aP0 = &xq[(4 * qg + 0) * 68];
    const float* aP1 = &xq[(4 * qg + 1) * 68];
    const float* aP2 = &xq[(4 * qg + 2) * 68];
    const float* aP3 = &xq[(4 * qg + 3) * 68];
    const float* bP0 = &xj[(4 * jg + 0) * 68];
    const float* bP1 = &xj[(4 * jg + 1) * 68];
    const float* bP2 = &xj[(4 * jg + 2) * 68];
    const float* bP3 = &xj[(4 * jg + 3) * 68];
    float* dW = &dist[4 * qg * 68 + 4 * jg];
    const float* drow = &dist[q * 68 + s * 16];
    const float* sjP = &sqj[4 * jg];
    u64* const buft = buf + t;
    u64* bufc = buft;

    u64 lst[KNN];
    #pragma unroll
    for (int k = 0; k < KNN; ++k) lst[k] = INIT_KEY;
    float tmax = 3.402823466e38f;
    int cnt = 0;

    for (int tile = 0; tile < NTILES; ++tile) {
        if constexpr (D == 3) {
            float sj[4];
            #pragma unroll
            for (int cc = 0; cc < 4; ++cc) sj[cc] = sjP[cc];
            float4 bx, by, bz;
            bx.x = xj[0 * 68 + 4 * jg + 0]; bx.y = xj[0 * 68 + 4 * jg + 1];
            bx.z = xj[0 * 68 + 4 * jg + 2]; bx.w = xj[0 * 68 + 4 * jg + 3];
            by.x = xj[1 * 68 + 4 * jg + 0]; by.y = xj[1 * 68 + 4 * jg + 1];
            by.z = xj[1 * 68 + 4 * jg + 2]; by.w = xj[1 * 68 + 4 * jg + 3];
            bz.x = xj[2 * 68 + 4 * jg + 0]; bz.y = xj[2 * 68 + 4 * jg + 1];
            bz.z = xj[2 * 68 + 4 * jg + 2]; bz.w = xj[2 * 68 + 4 * jg + 3];
            #pragma unroll
            for (int rr = 0; rr < 4; ++rr) {
                float4 dv;
                dv.x = sqq_r[rr] + sj[0] - 2.f * (aq[rr].x * bx.x + aq[rr].y * by.x + aq[rr].z * bz.x);
                dv.y = sqq_r[rr] + sj[1] - 2.f * (aq[rr].x * bx.y + aq[rr].y * by.y + aq[rr].z * bz.y);
                dv.z = sqq_r[rr] + sj[2] - 2.f * (aq[rr].x * bx.z + aq[rr].y * by.z + aq[rr].z * bz.z);
                dv.w = sqq_r[rr] + sj[3] - 2.f * (aq[rr].x * bx.w + aq[rr].y * by.w + aq[rr].z * bz.w);
                *(float4*)&dW[rr * 68] = dv;
            }
        } else {
            float acc[4][4];
            #pragma unroll
            for (int rr = 0; rr < 4; ++rr)
                #pragma unroll
                for (int cc = 0; cc < 4; ++cc) acc[rr][cc] = 0.f;
            #pragma unroll
            for (int k = 0; k < 16; ++k) {
                const int ko = 4 * k;
                const int kxo = 4 * ((k + jg) & 15);
                float4 a[4], bv[4];
                a[0] = *(const float4*)&aP0[ko];
                a[1] = *(const float4*)&aP1[ko];
                a[2] = *(const float4*)&aP2[ko];
                a[3] = *(const float4*)&aP3[ko];
                bv[0] = *(const float4*)&bP0[kxo];
                bv[1] = *(const float4*)&bP1[kxo];
                bv[2] = *(const float4*)&bP2[kxo];
                bv[3] = *(const float4*)&bP3[kxo];
                #pragma unroll
                for (int rr = 0; rr < 4; ++rr)
                    #pragma unroll
                    for (int cc = 0; cc < 4; ++cc) {
                        float v = acc[rr][cc];
                        v = fmaf(a[rr].x, bv[cc].x, v);
                        v = fmaf(a[rr].y, bv[cc].y, v);
                        v = fmaf(a[rr].z, bv[cc].z, v);
                        v = fmaf(a[rr].w, bv[cc].w, v);
                        acc[rr][cc] = v;
                    }
            }
            float sj[4];
            #pragma unroll
            for (int cc = 0; cc < 4; ++cc) sj[cc] = sjP[cc];
            #pragma unroll
            for (int rr = 0; rr < 4; ++rr) {
                float4 dv;
                dv.x = sqq_r[rr] + sj[0] - 2.f * acc[rr][0];
                dv.y = sqq_r[rr] + sj[1] - 2.f * acc[rr][1];
                dv.z = sqq_r[rr] + sj[2] - 2.f * acc[rr][2];
                dv.w = sqq_r[rr] + sj[3] - 2.f * acc[rr][3];
                *(float4*)&dW[rr * 68] = dv;
            }
        }
        __syncthreads();   // barrier1: dist ready; xj consumed

        if (tile + 1 < NTILES) {
            const int cb = (tile + 1) * TILE;
            if constexpr (D == 3) {
                if (t < 64) {
                    const float* row = Xb + (size_t)(cb + t) * 3;
                    xj[0 * 68 + t] = row[0];
                    xj[1 * 68 + t] = row[1];
                    xj[2 * 68 + t] = row[2];
                    sqj[t] = sqb[cb + t];
                }
            } else {
                #pragma unroll
                for (int ci = t; ci < 1024; ci += BTHR) {
                    const int r = ci >> 4, c4 = ci & 15;
                    const int c4s = (c4 + (r >> 2)) & 15;
                    *(float4*)&xj[r * 68 + 4 * c4s] =
                        *(const float4*)&Xb[(size_t)(cb + r) * 64 + 4 * c4];
                }
                if (t < 64) sqj[t] = sqb[cb + t];
            }
        }

        {
            const unsigned cbase = tile * TILE + s * 16;
            #pragma unroll
            for (int g = 0; g < 4; ++g) {
                const float4 dv = *(const float4*)&drow[g * 4];
                if (dv.x <= tmax) { *bufc = pack_key(dv.x, cbase + g * 4 + 0); bufc += BTHR; ++cnt; }
                if (dv.y <= tmax) { *bufc = pack_key(dv.y, cbase + g * 4 + 1); bufc += BTHR; ++cnt; }
                if (dv.z <= tmax) { *bufc = pack_key(dv.z, cbase + g * 4 + 2); bufc += BTHR; ++cnt; }
                if (dv.w <= tmax) { *bufc = pack_key(dv.w, cbase + g * 4 + 3); bufc += BTHR; ++cnt; }
                if (__any(cnt >= CAP)) { flush_buf(lst, buft, cnt, tmax); bufc = buft; }
            }
        }
        __syncthreads();   // barrier2: dist consumed; xj ready for next A
    }
    if (__any(cnt > 0)) flush_buf(lst, buft, cnt, tmax);

    #pragma unroll
    for (int k = 0; k < KNN; ++k) lists[t * KNN + k] = lst[k];
    __syncthreads();

    if (t < 64) {
        const u64* L0 = lists + (size_t)(t * 4 + 0) * KNN;
        const u64* L1 = L0 + KNN;
        const u64* L2 = L1 + KNN;
        const u64* L3 = L2 + KNN;
        int p0 = 0, p1 = 0, p2 = 0, p3 = 0;
        int* outp = knn_idx + ((size_t)b * NPTS + qbase + t) * KNN;
        for (int k = 0; k < KNN; ++k) {
            const u64 h0 = L0[p0], h1 = L1[p1], h2 = L2[p2], h3 = L3[p3];
            const u64 m01 = (h0 < h1) ? h0 : h1;
            const u64 m23 = (h2 < h3) ? h2 : h3;
            const u64 m   = (m01 < m23) ? m01 : m23;
            outp[k] = (int)(unsigned)(m & 0xffffffffu);
            if (m == h0) ++p0; else if (m == h1) ++p1; else if (m == h2) ++p2; else ++p3;
        }
    }
}

// ---------------------------------------------------------------------------
// per-point u = X @ W1b, c = X @ W1a - u + b1, FUSED squared norms (R14):
// sq summation order identical to the old sq_kernel (sequential d=0..D-1),
// so distances and ranking are bit-identical. uc now runs BEFORE knn.
// ---------------------------------------------------------------------------
template<int D>
__global__ __launch_bounds__(256) void uc_kernel(
    const float* __restrict__ X, const float* __restrict__ W1,
    const float* __restrict__ b1, float* __restrict__ u, float* __restrict__ cvec,
    float* __restrict__ sqv) {
    __shared__ float Xs[16 * D];
    const int n0 = blockIdx.x * 16;
    const int t = threadIdx.x;
    for (int i = t; i < 16 * D; i += 256)
        Xs[i] = X[(size_t)n0 * D + i];
    __syncthreads();

    if (t < 16) {
        float s = 0.f;
        #pragma unroll
        for (int d = 0; d < D; ++d) { const float v = Xs[t * D + d]; s += v * v; }
        sqv[n0 + t] = s;
    }

    const int o = t & 63;
    const int pg = t >> 6;
    float va[4] = {0.f, 0.f, 0.f, 0.f};
    float vb[4] = {0.f, 0.f, 0.f, 0.f};
    for (int d = 0; d < D; ++d) {
        const float wa = W1[d * 64 + o];
        const float wb = W1[(D + d) * 64 + o];
        #pragma unroll
        for (int pi = 0; pi < 4; ++pi) {
            const float x = Xs[(pg * 4 + pi) * D + d];
            va[pi] += x * wa;
            vb[pi] += x * wb;
        }
    }
    const float bo = b1[o];
    #pragma unroll
    for (int pi = 0; pi < 4; ++pi) {
        const size_t n = (size_t)n0 + pg * 4 + pi;
        u[n * 64 + o] = vb[pi];
        cvec[n * 64 + o] = va[pi] - vb[pi] + bo;
    }
}

// ---------------------------------------------------------------------------
// fused edge MLP + max aggregation (R12 4-pt version: 44 KB LDS, 3 blk/CU --
// R13 showed the 8-pt variant's 62.6 KB drops to 2 blk/CU and regresses).
// ---------------------------------------------------------------------------
__device__ __forceinline__ void gemm_acc(const float* __restrict__ Xs,
                                         const float* __restrict__ Ws,
                                         const float* __restrict__ bias,
                                         float (&acc)[5][4], const int t) {
    const int rg = t >> 4, og = t & 15;
    #pragma unroll
    for (int oc = 0; oc < 4; ++oc) {
        const float bb = bias[4 * og + oc];
        #pragma unroll
        for (int rr = 0; rr < 5; ++rr) acc[rr][oc] = bb;
    }
    #pragma unroll
    for (int k4 = 0; k4 < 16; ++k4) {
        float4 xv[5];
        #pragma unroll
        for (int rr = 0; rr < 5; ++rr)
            xv[rr] = *(const float4*)&Xs[(5 * rg + rr) * 68 + 4 * k4];
        float4 wv[4];
        #pragma unroll
        for (int kk = 0; kk < 4; ++kk)
            wv[kk] = *(const float4*)&Ws[(4 * k4 + kk) * 64 + 4 * og];
        #pragma unroll
        for (int rr = 0; rr < 5; ++rr) {
            acc[rr][0] += xv[rr].x * wv[0].x + xv[rr].y * wv[1].x + xv[rr].z * wv[2].x + xv[rr].w * wv[3].x;
            acc[rr][1] += xv[rr].x * wv[0].y + xv[rr].y * wv[1].y + xv[rr].z * wv[2].y + xv[rr].w * wv[3].y;
            acc[rr][2] += xv[rr].x * wv[0].z + xv[rr].y * wv[1].z + xv[rr].z * wv[2].z + xv[rr].w * wv[3].z;
            acc[rr][3] += xv[rr].x * wv[0].w + xv[rr].y * wv[1].w + xv[rr].z * wv[2].w + xv[rr].w * wv[3].w;
        }
    }
}

__global__ __launch_bounds__(256) void edge_kernel(
    const float* __restrict__ u, const float* __restrict__ cvec,
    const int* __restrict__ knn_idx,
    const float* __restrict__ W2, const float* __restrict__ b2,
    const float* __restrict__ W3, const float* __restrict__ b3,
    float* __restrict__ out) {
    __shared__ alignas(16) float h1s[80 * 68];
    __shared__ alignas(16) float Ws[64 * 64];
    __shared__ float cs[256];
    __shared__ float mxs[16 * 64];
    __shared__ int idxs[80];

    const int t = threadIdx.x;
    const int p0 = blockIdx.x * 4;
    const int b = p0 >> 12;

    cs[t] = cvec[(size_t)p0 * 64 + t];
    if (t < 80) idxs[t] = knn_idx[(size_t)p0 * KNN + t];
    for (int i = t; i < 4096; i += 256) Ws[i] = W2[i];
    __syncthreads();

    {   // h1 = lrelu(c_i + u_j)
        const int wave = t >> 6, lane = t & 63;
        for (int e = wave; e < 80; e += 4) {
            const int j = idxs[e];
            const float val = u[((size_t)(b << 12) + j) * 64 + lane];
            const float pre = cs[(e / 20) * 64 + lane] + val;
            h1s[e * 68 + lane] = (pre > 0.f) ? pre : SLOPE * pre;
        }
    }
    __syncthreads();

    float acc[5][4];
    gemm_acc(h1s, Ws, b2, acc, t);      // GEMM1
    __syncthreads();

    {   // write h2 back into h1s; stage W3
        const int rg = t >> 4, og = t & 15;
        #pragma unroll
        for (int rr = 0; rr < 5; ++rr)
            #pragma unroll
            for (int oc = 0; oc < 4; ++oc) {
                float v = acc[rr][oc];
                v = (v > 0.f) ? v : SLOPE * v;
                h1s[(5 * rg + rr) * 68 + 4 * og + oc] = v;
            }
        for (int i = t; i < 4096; i += 256) Ws[i] = W3[i];
    }
    __syncthreads();

    gemm_acc(h1s, Ws, b3, acc, t);      // GEMM2
    {   // max over each thread's 5 rows (within one point: 20 % 5 == 0)
        const int rg = t >> 4, og = t & 15;
        #pragma unroll
        for (int oc = 0; oc < 4; ++oc) {
            float m = -1e30f;
            #pragma unroll
            for (int rr = 0; rr < 5; ++rr) {
                float v = acc[rr][oc];
                v = (v > 0.f) ? v : SLOPE * v;
                m = fmaxf(m, v);
            }
            mxs[rg * 64 + 4 * og + oc] = m;
        }
    }
    __syncthreads();

    const int p = t >> 6, col = t & 63;
    const float m = fmaxf(fmaxf(mxs[(4 * p + 0) * 64 + col], mxs[(4 * p + 1) * 64 + col]),
                          fmaxf(mxs[(4 * p + 2) * 64 + col], mxs[(4 * p + 3) * 64 + col]));
    out[(size_t)(p0 + p) * 64 + col] = m;
}

// ---------------------------------------------------------------------------
extern "C" void kernel_launch(void* const* d_in, const int* in_sizes, int n_in,
                              void* d_out, int out_size, void* d_ws, size_t ws_size,
                              hipStream_t stream) {
    const float* pos = (const float*)d_in[0];
    const float* w11 = (const float*)d_in[1];  const float* b11 = (const float*)d_in[2];
    const float* w12 = (const float*)d_in[3];  const float* b12 = (const float*)d_in[4];
    const float* w13 = (const float*)d_in[5];  const float* b13 = (const float*)d_in[6];
    const float* w21 = (const float*)d_in[7];  const float* b21 = (const float*)d_in[8];
    const float* w22 = (const float*)d_in[9];  const float* b22 = (const float*)d_in[10];
    const float* w23 = (const float*)d_in[11]; const float* b23 = (const float*)d_in[12];
    const float* w31 = (const float*)d_in[13]; const float* b31 = (const float*)d_in[14];
    const float* w32 = (const float*)d_in[15]; const float* b32 = (const float*)d_in[16];
    const float* w33 = (const float*)d_in[17]; const float* b33 = (const float*)d_in[18];

    const int BN = BATCH * NPTS;   // 32768
    // Simple workspace (no aliasing): [sqb][idx][x1][u][c][x2] = 36.3 MB
    float* ws = (float*)d_ws;
    float* sqb = ws;                                  // [BN]
    int*   idx = (int*)(sqb + BN);                    // [BN][20]
    float* x1  = (float*)(idx + (size_t)BN * KNN);    // [BN][64]
    float* ubuf = x1 + (size_t)BN * 64;               // [BN][64]
    float* cbuf = ubuf + (size_t)BN * 64;             // [BN][64]
    float* x2  = cbuf + (size_t)BN * 64;              // [BN][64]

    const dim3 knn_grid(NPTS / 64, BATCH);            // (64, 8) = 512 blocks

    // ---- EdgeConv 1 (D=3): uc (computes u,c,sq) -> knn -> edge
    uc_kernel<3><<<BN / 16, 256, 0, stream>>>(pos, w11, b11, ubuf, cbuf, sqb);
    knn3_kernel<3><<<knn_grid, BTHR, 0, stream>>>(pos, sqb, idx);
    edge_kernel<<<BN / 4, 256, 0, stream>>>(ubuf, cbuf, idx, w12, b12, w13, b13, x1);

    // ---- EdgeConv 2 (D=64)
    uc_kernel<64><<<BN / 16, 256, 0, stream>>>(x1, w21, b21, ubuf, cbuf, sqb);
    knn3_kernel<64><<<knn_grid, BTHR, 0, stream>>>(x1, sqb, idx);
    edge_kernel<<<BN / 4, 256, 0, stream>>>(ubuf, cbuf, idx, w22, b22, w23, b23, x2);

    // ---- EdgeConv 3 (D=64)
    uc_kernel<64><<<BN / 16, 256, 0, stream>>>(x2, w31, b31, ubuf, cbuf, sqb);
    knn3_kernel<64><<<knn_grid, BTHR, 0, stream>>>(x2, sqb, idx);
    edge_kernel<<<BN / 4, 256, 0, stream>>>(ubuf, cbuf, idx, w32, b32, w33, b33, (float*)d_out);
}